// Round 6
// baseline (551.119 us; speedup 1.0000x reference)
//
#include <hip/hip_runtime.h>
#include <cstdint>

#define BB 32
#define PP 131072
#define NEG_RATIO 3

typedef float v4f __attribute__((ext_vector_type(4)));
typedef float v2f __attribute__((ext_vector_type(2)));

// Workspace accumulators (zeroed via hipMemsetAsync each launch).
struct Ws {
  float sum_sl1[BB];     // per-batch sum of smoothL1 * pos
  float sum_ce_all[BB];  // per-batch sum of CE over all priors
  float sum_ce_pos[BB];  // per-batch sum of CE over positives
  float ce_neg[BB];      // per-batch CE sum over selected negatives (case-2 only)
  int   num_pos[BB];
};

__device__ __forceinline__ float sl1sum(v4f a, v4f b) {
  float dx = fabsf(a.x - b.x), dy = fabsf(a.y - b.y),
        dz = fabsf(a.z - b.z), dw = fabsf(a.w - b.w);
  float sx = dx < 1.0f ? 0.5f * dx * dx : dx - 0.5f;
  float sy = dy < 1.0f ? 0.5f * dy * dy : dy - 0.5f;
  float sz = dz < 1.0f ? 0.5f * dz * dz : dz - 0.5f;
  float sw = dw < 1.0f ? 0.5f * dw * dw : dw - 0.5f;
  return (sx + sy) + (sz + sw);
}

__device__ __forceinline__ float ce_fast(float c0, float c1, int t) {
  float m = fmaxf(c0, c1);
  float d = fabsf(c0 - c1);
  float lse = m + __logf(1.0f + __expf(-d));
  return lse - (t ? c1 : c0);
}

// exact-ish version for the (never-taken on bench data) select path
__device__ __forceinline__ float ce_of(float c0, float c1, int t) {
  float m = fmaxf(c0, c1), mn = fminf(c0, c1);
  float lse = m + log1pf(expf(mn - m));
  return lse - (t ? c1 : c0);
}

// ---------------- K_fused: single pass, 2 strided priors/thread ----------------
// 8192 blocks x 256 thr; block b owns priors [512b, 512b+512), all in batch
// b>>8. Thread t handles p0 = 512b+t and p0+256. Every load is lane-unit-
// stride. Plain loads (asm/DMA variants measured worse, R4/R5); per-wave
// atomics (1024 adds/address over ~65us -- negligible contention).
__global__ __launch_bounds__(256) void k_fused(
    const v4f* __restrict__ loc, const v2f* __restrict__ cf2,
    const v4f* __restrict__ loct, const int* __restrict__ tt,
    Ws* __restrict__ ws) {
  const int tid = threadIdx.x;
  const int b = blockIdx.x;
  const int batch = b >> 8;        // 256 blocks per batch
  const int p0 = b * 512 + tid;

  const v4f l0 = __builtin_nontemporal_load(loc + p0);
  const v4f l1 = __builtin_nontemporal_load(loc + p0 + 256);
  const v4f g0 = __builtin_nontemporal_load(loct + p0);
  const v4f g1 = __builtin_nontemporal_load(loct + p0 + 256);
  const v2f c0 = cf2[p0];
  const v2f c1 = cf2[p0 + 256];
  const int t0 = tt[p0];
  const int t1 = tt[p0 + 256];

  const float ce0 = ce_fast(c0.x, c0.y, t0);
  const float ce1 = ce_fast(c1.x, c1.y, t1);
  const float s0 = sl1sum(l0, g0);
  const float s1 = sl1sum(l1, g1);
  const float m0 = t0 > 0 ? 1.0f : 0.0f;
  const float m1 = t1 > 0 ? 1.0f : 0.0f;

  float a_all = ce0 + ce1;
  float a_pos = m0 * ce0 + m1 * ce1;
  float a_sl1 = m0 * s0 + m1 * s1;
  int   a_np  = (t0 > 0) + (t1 > 0);

#pragma unroll
  for (int off = 32; off; off >>= 1) {
    a_all += __shfl_down(a_all, off);
    a_pos += __shfl_down(a_pos, off);
    a_sl1 += __shfl_down(a_sl1, off);
    a_np  += __shfl_down(a_np, off);
  }
  if ((tid & 63) == 0) {
    atomicAdd(&ws->sum_ce_all[batch], a_all);
    atomicAdd(&ws->sum_ce_pos[batch], a_pos);
    atomicAdd(&ws->sum_sl1[batch],    a_sl1);
    atomicAdd(&ws->num_pos[batch],    a_np);
  }
}

// ---------------- K2: general top-k negative selection (case 2) ----------------
// Only runs for batches where num_neg < (P - num_pos). For the bench data this
// never triggers (num_neg = P-1 >= M), so the block exits immediately.
__global__ __launch_bounds__(256) void k_select(
    const float2* __restrict__ conf, const int* __restrict__ conft,
    Ws* __restrict__ ws) {
  const int b = blockIdx.x;
  const int npos = ws->num_pos[b];
  const long long M = (long long)PP - npos;
  long long k = (long long)NEG_RATIO * npos;
  if (k > PP - 1) k = PP - 1;
  if (k >= M) return;   // case 1: sel == everything, finalize handles it
  if (k <= 0) return;   // no negatives selected

  const int tid = threadIdx.x;
  const int rowbase = b * PP;

  __shared__ unsigned hist[2048];
  __shared__ unsigned sh_prefix;
  __shared__ long long sh_kk;

  unsigned prefix = 0;
  long long kk = k;
  const int shifts[3] = {21, 10, 0};
  const int widths[3] = {11, 11, 10};

  for (int pass = 0; pass < 3; ++pass) {
    const int shift = shifts[pass], width = widths[pass];
    const unsigned mask = (1u << width) - 1u;
    for (int j = tid; j < 2048; j += 256) hist[j] = 0;
    __syncthreads();
    for (int i = tid; i < PP; i += 256) {
      const float2 c = conf[rowbase + i];
      const int t = conft[rowbase + i];
      const float score = (t > 0) ? 0.0f : ce_of(c.x, c.y, t);
      const unsigned u = __float_as_uint(score);
      const bool match = (pass == 0) || ((u >> (shift + width)) == prefix);
      if (match) atomicAdd(&hist[(u >> shift) & mask], 1u);
    }
    __syncthreads();
    if (tid == 0) {
      long long c = 0;
      int d = (int)mask;
      for (; d >= 0; --d) {
        c += hist[d];
        if (c >= kk) break;
      }
      if (d < 0) d = 0;  // safety; invariant guarantees break
      sh_prefix = (prefix << width) | (unsigned)d;
      sh_kk = kk - (c - (long long)hist[d]);
    }
    __syncthreads();
    prefix = sh_prefix;
    kk = sh_kk;
    __syncthreads();
  }

  // prefix == T bits (k-th largest score). kk = #ties to include, ascending
  // index order (stable argsort semantics).
  const unsigned Tbits = prefix;
  double local_ce = 0.0;
  __shared__ unsigned wavecnt[4];
  __shared__ long long s_rt;
  if (tid == 0) s_rt = 0;
  __syncthreads();
  const int lane = tid & 63, wave = tid >> 6;

  for (int basei = 0; basei < PP; basei += 256) {
    const int i = basei + tid;
    const float2 c = conf[rowbase + i];
    const int t = conft[rowbase + i];
    const float ce = ce_of(c.x, c.y, t);
    const float score = (t > 0) ? 0.0f : ce;
    const unsigned u = __float_as_uint(score);
    const bool gt = u > Tbits;
    const bool eq = (u == Tbits);
    const unsigned long long bal = __ballot(eq ? 1 : 0);
    if (lane == 0) wavecnt[wave] = (unsigned)__popcll(bal);
    __syncthreads();
    long long cross = s_rt;
    for (int w = 0; w < wave; ++w) cross += wavecnt[w];
    const long long myord = cross + __popcll(bal & ((1ULL << lane) - 1ULL));
    if (gt || (eq && myord < kk)) local_ce += (double)ce;
    __syncthreads();
    if (tid == 0) s_rt += (long long)wavecnt[0] + wavecnt[1] + wavecnt[2] + wavecnt[3];
    __syncthreads();
  }

#pragma unroll
  for (int off = 32; off; off >>= 1) local_ce += __shfl_down(local_ce, off);
  __shared__ double s_ce[4];
  if (lane == 0) s_ce[wave] = local_ce;
  __syncthreads();
  if (tid == 0) ws->ce_neg[b] = (float)(s_ce[0] + s_ce[1] + s_ce[2] + s_ce[3]);
}

// ---------------- K3: finalize ----------------
__global__ __launch_bounds__(64) void k_final(const Ws* __restrict__ ws,
                                              float* __restrict__ out) {
  const int tid = threadIdx.x;
  double np_d = 0.0, ce_sel = 0.0, cnt = 0.0, sl1 = 0.0;
  if (tid < BB) {
    const int npos = ws->num_pos[tid];
    const long long M = (long long)PP - npos;
    long long k = (long long)NEG_RATIO * npos;
    if (k > PP - 1) k = PP - 1;
    np_d = (double)npos;
    sl1 = (double)ws->sum_sl1[tid];
    if (k >= M) {  // case 1: sel covers every prior
      ce_sel = (double)ws->sum_ce_all[tid];
      cnt = (double)PP;
    } else {
      const long long kc = k > 0 ? k : 0;
      ce_sel = (double)ws->sum_ce_pos[tid] + (double)ws->ce_neg[tid];
      cnt = (double)(npos + kc);
    }
  }
#pragma unroll
  for (int off = 32; off; off >>= 1) {
    np_d   += __shfl_down(np_d, off);
    ce_sel += __shfl_down(ce_sel, off);
    cnt    += __shfl_down(cnt, off);
    sl1    += __shfl_down(sl1, off);
  }
  if (tid == 0) {
    const double N = np_d;
    out[0] = (float)(sl1 / (4.0 * N * N));
    out[1] = (float)(ce_sel / cnt / N);
  }
}

extern "C" void kernel_launch(void* const* d_in, const int* in_sizes, int n_in,
                              void* d_out, int out_size, void* d_ws, size_t ws_size,
                              hipStream_t stream) {
  const v4f*    loc   = (const v4f*)d_in[0];
  const v2f*    cf2   = (const v2f*)d_in[1];
  const float2* conf  = (const float2*)d_in[1];
  const v4f*    loct  = (const v4f*)d_in[2];
  const int*    cnft  = (const int*)d_in[3];
  Ws* ws = (Ws*)d_ws;

  hipMemsetAsync(d_ws, 0, sizeof(Ws), stream);
  k_fused<<<dim3((BB * PP) / 512), dim3(256), 0, stream>>>(loc, cf2, loct, cnft, ws);
  k_select<<<dim3(BB), dim3(256), 0, stream>>>(conf, cnft, ws);
  k_final<<<dim3(1), dim3(64), 0, stream>>>(ws, (float*)d_out);
}

// Round 7
// 193.242 us; speedup vs baseline: 2.8520x; 2.8520x over previous
//
#include <hip/hip_runtime.h>
#include <cstdint>

#define BB 32
#define PP 131072
#define NEG_RATIO 3
#define NBLK 2048            // k_main blocks; 64 per batch

typedef float v4f __attribute__((ext_vector_type(4)));
typedef float v2f __attribute__((ext_vector_type(2)));

// One 16-byte partial per k_main block — plain stores, zero contention.
// (R1-R6 lesson: same-line global atomicAdds serialize at ~25 ns/op; 16k
// ops/line = 410 us. Model fit R6 419 us, R4 110 us, R3 50 us.)
struct Partial {
  float ce_all, ce_pos, sl1;
  int np;
};

struct Ws {
  float sum_sl1[BB];
  float sum_ce_all[BB];
  float sum_ce_pos[BB];
  float ce_neg[BB];
  int   num_pos[BB];
  Partial part[NBLK];
};

__device__ __forceinline__ float sl1sum(v4f a, v4f b) {
  float dx = fabsf(a.x - b.x), dy = fabsf(a.y - b.y),
        dz = fabsf(a.z - b.z), dw = fabsf(a.w - b.w);
  float sx = dx < 1.0f ? 0.5f * dx * dx : dx - 0.5f;
  float sy = dy < 1.0f ? 0.5f * dy * dy : dy - 0.5f;
  float sz = dz < 1.0f ? 0.5f * dz * dz : dz - 0.5f;
  float sw = dw < 1.0f ? 0.5f * dw * dw : dw - 0.5f;
  return (sx + sy) + (sz + sw);
}

__device__ __forceinline__ float ce_fast(float c0, float c1, int t) {
  float m = fmaxf(c0, c1);
  float d = fabsf(c0 - c1);
  float lse = m + __logf(1.0f + __expf(-d));
  return lse - (t ? c1 : c0);
}

// exact-ish version for the (never-taken on bench data) select path
__device__ __forceinline__ float ce_of(float c0, float c1, int t) {
  float m = fmaxf(c0, c1), mn = fminf(c0, c1);
  float lse = m + log1pf(expf(mn - m));
  return lse - (t ? c1 : c0);
}

// ---------------- K_main: fused pass, block-level partials, NO atomics ----------
// 2048 blocks x 256 thr; block covers 2048 contiguous priors (one batch),
// thread handles 8 priors at +256 stride (R1's structure — best streamer).
__global__ __launch_bounds__(256) void k_main(
    const v4f* __restrict__ loc, const v2f* __restrict__ cf2,
    const v4f* __restrict__ loct, const int* __restrict__ tt,
    Partial* __restrict__ part) {
  const int tid = threadIdx.x;
  const int base = blockIdx.x * 2048;

  float a_all = 0.f, a_pos = 0.f, a_sl1 = 0.f;
  int np = 0;

#pragma unroll
  for (int k = 0; k < 8; ++k) {
    const int i = base + k * 256 + tid;
    const v4f l = loc[i];
    const v4f g = loct[i];
    const v2f c = cf2[i];
    const int t = tt[i];

    const float ce = ce_fast(c.x, c.y, t);
    const float s  = sl1sum(l, g);
    const float m  = t > 0 ? 1.0f : 0.0f;
    a_all += ce;
    a_pos += m * ce;
    a_sl1 += m * s;
    np    += (t > 0);
  }

#pragma unroll
  for (int off = 32; off; off >>= 1) {
    a_all += __shfl_down(a_all, off);
    a_pos += __shfl_down(a_pos, off);
    a_sl1 += __shfl_down(a_sl1, off);
    np    += __shfl_down(np, off);
  }

  __shared__ float s1[4], s2[4], s3[4];
  __shared__ int s4[4];
  const int wave = tid >> 6, lane = tid & 63;
  if (lane == 0) { s1[wave] = a_all; s2[wave] = a_pos; s3[wave] = a_sl1; s4[wave] = np; }
  __syncthreads();
  if (tid == 0) {
    Partial p;
    p.ce_all = (s1[0] + s1[1]) + (s1[2] + s1[3]);
    p.ce_pos = (s2[0] + s2[1]) + (s2[2] + s2[3]);
    p.sl1    = (s3[0] + s3[1]) + (s3[2] + s3[3]);
    p.np     = s4[0] + s4[1] + s4[2] + s4[3];
    part[blockIdx.x] = p;  // plain 16B store, disjoint slot
  }
}

// ---------------- K_reduce: fold 64 partials/batch into finals ----------------
__global__ __launch_bounds__(64) void k_reduce(const Partial* __restrict__ part,
                                               Ws* __restrict__ ws) {
  const int b = blockIdx.x;      // batch
  const int lane = threadIdx.x;  // 0..63
  Partial p = part[b * 64 + lane];
  float all = p.ce_all, pos = p.ce_pos, sl1 = p.sl1;
  int np = p.np;
#pragma unroll
  for (int off = 32; off; off >>= 1) {
    all += __shfl_down(all, off);
    pos += __shfl_down(pos, off);
    sl1 += __shfl_down(sl1, off);
    np  += __shfl_down(np, off);
  }
  if (lane == 0) {
    ws->sum_ce_all[b] = all;
    ws->sum_ce_pos[b] = pos;
    ws->sum_sl1[b]    = sl1;
    ws->num_pos[b]    = np;
  }
}

// ---------------- K2: general top-k negative selection (case 2) ----------------
// Only runs for batches where num_neg < (P - num_pos). For the bench data this
// never triggers (num_neg = P-1 >= M), so the block exits immediately.
__global__ __launch_bounds__(256) void k_select(
    const float2* __restrict__ conf, const int* __restrict__ conft,
    Ws* __restrict__ ws) {
  const int b = blockIdx.x;
  const int npos = ws->num_pos[b];
  const long long M = (long long)PP - npos;
  long long k = (long long)NEG_RATIO * npos;
  if (k > PP - 1) k = PP - 1;
  if (k >= M) return;   // case 1: sel == everything, finalize handles it
  if (k <= 0) return;   // no negatives selected

  const int tid = threadIdx.x;
  const int rowbase = b * PP;

  __shared__ unsigned hist[2048];
  __shared__ unsigned sh_prefix;
  __shared__ long long sh_kk;

  unsigned prefix = 0;
  long long kk = k;
  const int shifts[3] = {21, 10, 0};
  const int widths[3] = {11, 11, 10};

  for (int pass = 0; pass < 3; ++pass) {
    const int shift = shifts[pass], width = widths[pass];
    const unsigned mask = (1u << width) - 1u;
    for (int j = tid; j < 2048; j += 256) hist[j] = 0;
    __syncthreads();
    for (int i = tid; i < PP; i += 256) {
      const float2 c = conf[rowbase + i];
      const int t = conft[rowbase + i];
      const float score = (t > 0) ? 0.0f : ce_of(c.x, c.y, t);
      const unsigned u = __float_as_uint(score);
      const bool match = (pass == 0) || ((u >> (shift + width)) == prefix);
      if (match) atomicAdd(&hist[(u >> shift) & mask], 1u);
    }
    __syncthreads();
    if (tid == 0) {
      long long c = 0;
      int d = (int)mask;
      for (; d >= 0; --d) {
        c += hist[d];
        if (c >= kk) break;
      }
      if (d < 0) d = 0;  // safety; invariant guarantees break
      sh_prefix = (prefix << width) | (unsigned)d;
      sh_kk = kk - (c - (long long)hist[d]);
    }
    __syncthreads();
    prefix = sh_prefix;
    kk = sh_kk;
    __syncthreads();
  }

  // prefix == T bits (k-th largest score). kk = #ties to include, ascending
  // index order (stable argsort semantics).
  const unsigned Tbits = prefix;
  double local_ce = 0.0;
  __shared__ unsigned wavecnt[4];
  __shared__ long long s_rt;
  if (tid == 0) s_rt = 0;
  __syncthreads();
  const int lane = tid & 63, wave = tid >> 6;

  for (int basei = 0; basei < PP; basei += 256) {
    const int i = basei + tid;
    const float2 c = conf[rowbase + i];
    const int t = conft[rowbase + i];
    const float ce = ce_of(c.x, c.y, t);
    const float score = (t > 0) ? 0.0f : ce;
    const unsigned u = __float_as_uint(score);
    const bool gt = u > Tbits;
    const bool eq = (u == Tbits);
    const unsigned long long bal = __ballot(eq ? 1 : 0);
    if (lane == 0) wavecnt[wave] = (unsigned)__popcll(bal);
    __syncthreads();
    long long cross = s_rt;
    for (int w = 0; w < wave; ++w) cross += wavecnt[w];
    const long long myord = cross + __popcll(bal & ((1ULL << lane) - 1ULL));
    if (gt || (eq && myord < kk)) local_ce += (double)ce;
    __syncthreads();
    if (tid == 0) s_rt += (long long)wavecnt[0] + wavecnt[1] + wavecnt[2] + wavecnt[3];
    __syncthreads();
  }

#pragma unroll
  for (int off = 32; off; off >>= 1) local_ce += __shfl_down(local_ce, off);
  __shared__ double s_ce[4];
  if (lane == 0) s_ce[wave] = local_ce;
  __syncthreads();
  if (tid == 0) ws->ce_neg[b] = (float)(s_ce[0] + s_ce[1] + s_ce[2] + s_ce[3]);
}

// ---------------- K3: finalize ----------------
__global__ __launch_bounds__(64) void k_final(const Ws* __restrict__ ws,
                                              float* __restrict__ out) {
  const int tid = threadIdx.x;
  double np_d = 0.0, ce_sel = 0.0, cnt = 0.0, sl1 = 0.0;
  if (tid < BB) {
    const int npos = ws->num_pos[tid];
    const long long M = (long long)PP - npos;
    long long k = (long long)NEG_RATIO * npos;
    if (k > PP - 1) k = PP - 1;
    np_d = (double)npos;
    sl1 = (double)ws->sum_sl1[tid];
    if (k >= M) {  // case 1: sel covers every prior
      ce_sel = (double)ws->sum_ce_all[tid];
      cnt = (double)PP;
    } else {
      const long long kc = k > 0 ? k : 0;
      ce_sel = (double)ws->sum_ce_pos[tid] + (double)ws->ce_neg[tid];
      cnt = (double)(npos + kc);
    }
  }
#pragma unroll
  for (int off = 32; off; off >>= 1) {
    np_d   += __shfl_down(np_d, off);
    ce_sel += __shfl_down(ce_sel, off);
    cnt    += __shfl_down(cnt, off);
    sl1    += __shfl_down(sl1, off);
  }
  if (tid == 0) {
    const double N = np_d;
    out[0] = (float)(sl1 / (4.0 * N * N));
    out[1] = (float)(ce_sel / cnt / N);
  }
}

extern "C" void kernel_launch(void* const* d_in, const int* in_sizes, int n_in,
                              void* d_out, int out_size, void* d_ws, size_t ws_size,
                              hipStream_t stream) {
  const v4f*    loc   = (const v4f*)d_in[0];
  const v2f*    cf2   = (const v2f*)d_in[1];
  const float2* conf  = (const float2*)d_in[1];
  const v4f*    loct  = (const v4f*)d_in[2];
  const int*    cnft  = (const int*)d_in[3];
  Ws* ws = (Ws*)d_ws;

  hipMemsetAsync(d_ws, 0, sizeof(Ws), stream);
  k_main<<<dim3(NBLK), dim3(256), 0, stream>>>(loc, cf2, loct, cnft, ws->part);
  k_reduce<<<dim3(BB), dim3(64), 0, stream>>>(ws->part, ws);
  k_select<<<dim3(BB), dim3(256), 0, stream>>>(conf, cnft, ws);
  k_final<<<dim3(1), dim3(64), 0, stream>>>(ws, (float*)d_out);
}

// Round 8
// 178.719 us; speedup vs baseline: 3.0837x; 1.0813x over previous
//
#include <hip/hip_runtime.h>
#include <cstdint>

#define BB 32
#define PP 131072
#define NEG_RATIO 3
#define NBLK 2048            // k_main blocks; 64 per batch

typedef float v4f __attribute__((ext_vector_type(4)));
typedef float v2f __attribute__((ext_vector_type(2)));

// One 16-byte partial per k_main block — plain stores, zero contention.
// (R6 lesson: same-line global atomicAdds serialize ~25 ns/op.)
struct Partial {
  float ce_all, ce_pos, sl1;
  int np;
};

struct Ws {
  float sum_sl1[BB];
  float sum_ce_all[BB];
  float sum_ce_pos[BB];
  float ce_neg[BB];
  int   num_pos[BB];
  Partial part[NBLK];
};

__device__ __forceinline__ float sl1sum(v4f a, v4f b) {
  float dx = fabsf(a.x - b.x), dy = fabsf(a.y - b.y),
        dz = fabsf(a.z - b.z), dw = fabsf(a.w - b.w);
  float sx = dx < 1.0f ? 0.5f * dx * dx : dx - 0.5f;
  float sy = dy < 1.0f ? 0.5f * dy * dy : dy - 0.5f;
  float sz = dz < 1.0f ? 0.5f * dz * dz : dz - 0.5f;
  float sw = dw < 1.0f ? 0.5f * dw * dw : dw - 0.5f;
  return (sx + sy) + (sz + sw);
}

__device__ __forceinline__ float ce_fast(float c0, float c1, int t) {
  float m = fmaxf(c0, c1);
  float d = fabsf(c0 - c1);
  float lse = m + __logf(1.0f + __expf(-d));
  return lse - (t ? c1 : c0);
}

// exact-ish version for the (never-taken on bench data) select path
__device__ __forceinline__ float ce_of(float c0, float c1, int t) {
  float m = fmaxf(c0, c1), mn = fminf(c0, c1);
  float lse = m + log1pf(expf(mn - m));
  return lse - (t ? c1 : c0);
}

// ---------------- K_main: fused pass, partial stores, MLP via occupancy hint --
// __launch_bounds__(256, 2): min 2 waves/EU -> ~256 VGPR budget/wave. This is
// the scheduler input R1-R7 never changed; at the default max-occupancy target
// the AMDGPU scheduler shrank every load live-range (VGPR 16-40, 1 load in
// flight, 2.4-3.0 TB/s wall). With the budget raised, the 32-load batch below
// can stay resident: ~5.6 KB in flight/wave, ~45 KB/CU at 8 waves/CU.
__global__ __launch_bounds__(256, 2) void k_main(
    const v4f* __restrict__ loc, const v2f* __restrict__ cf2,
    const v4f* __restrict__ loct, const int* __restrict__ tt,
    Partial* __restrict__ part) {
  const int tid = threadIdx.x;
  const int base = blockIdx.x * 2048;

  v4f l[8], g[8];
  v2f c[8];
  int t[8];
#pragma unroll
  for (int k = 0; k < 8; ++k) {
    const int i = base + k * 256 + tid;
    l[k] = __builtin_nontemporal_load(loc + i);   // zero-reuse stream
    g[k] = __builtin_nontemporal_load(loct + i);  // zero-reuse stream
    c[k] = cf2[i];                                // re-read by k_select
    t[k] = tt[i];                                 // re-read by k_select
  }

  float a_all = 0.f, a_pos = 0.f, a_sl1 = 0.f;
  int np = 0;
#pragma unroll
  for (int k = 0; k < 8; ++k) {
    const float ce = ce_fast(c[k].x, c[k].y, t[k]);
    const float s  = sl1sum(l[k], g[k]);
    const float m  = t[k] > 0 ? 1.0f : 0.0f;
    a_all += ce;
    a_pos += m * ce;
    a_sl1 += m * s;
    np    += (t[k] > 0);
  }

#pragma unroll
  for (int off = 32; off; off >>= 1) {
    a_all += __shfl_down(a_all, off);
    a_pos += __shfl_down(a_pos, off);
    a_sl1 += __shfl_down(a_sl1, off);
    np    += __shfl_down(np, off);
  }

  __shared__ float s1[4], s2[4], s3[4];
  __shared__ int s4[4];
  const int wave = tid >> 6, lane = tid & 63;
  if (lane == 0) { s1[wave] = a_all; s2[wave] = a_pos; s3[wave] = a_sl1; s4[wave] = np; }
  __syncthreads();
  if (tid == 0) {
    Partial p;
    p.ce_all = (s1[0] + s1[1]) + (s1[2] + s1[3]);
    p.ce_pos = (s2[0] + s2[1]) + (s2[2] + s2[3]);
    p.sl1    = (s3[0] + s3[1]) + (s3[2] + s3[3]);
    p.np     = s4[0] + s4[1] + s4[2] + s4[3];
    part[blockIdx.x] = p;  // plain 16B store, disjoint slot
  }
}

// ---------------- K_reduce: fold 64 partials/batch into finals ----------------
__global__ __launch_bounds__(64) void k_reduce(const Partial* __restrict__ part,
                                               Ws* __restrict__ ws) {
  const int b = blockIdx.x;      // batch
  const int lane = threadIdx.x;  // 0..63
  Partial p = part[b * 64 + lane];
  float all = p.ce_all, pos = p.ce_pos, sl1 = p.sl1;
  int np = p.np;
#pragma unroll
  for (int off = 32; off; off >>= 1) {
    all += __shfl_down(all, off);
    pos += __shfl_down(pos, off);
    sl1 += __shfl_down(sl1, off);
    np  += __shfl_down(np, off);
  }
  if (lane == 0) {
    ws->sum_ce_all[b] = all;
    ws->sum_ce_pos[b] = pos;
    ws->sum_sl1[b]    = sl1;
    ws->num_pos[b]    = np;
  }
}

// ---------------- K2: general top-k negative selection (case 2) ----------------
// Only runs for batches where num_neg < (P - num_pos). For the bench data this
// never triggers (num_neg = P-1 >= M), so the block exits immediately.
__global__ __launch_bounds__(256) void k_select(
    const float2* __restrict__ conf, const int* __restrict__ conft,
    Ws* __restrict__ ws) {
  const int b = blockIdx.x;
  const int npos = ws->num_pos[b];
  const long long M = (long long)PP - npos;
  long long k = (long long)NEG_RATIO * npos;
  if (k > PP - 1) k = PP - 1;
  if (k >= M) return;   // case 1: sel == everything, finalize handles it
  if (k <= 0) return;   // no negatives selected

  const int tid = threadIdx.x;
  const int rowbase = b * PP;

  __shared__ unsigned hist[2048];
  __shared__ unsigned sh_prefix;
  __shared__ long long sh_kk;

  unsigned prefix = 0;
  long long kk = k;
  const int shifts[3] = {21, 10, 0};
  const int widths[3] = {11, 11, 10};

  for (int pass = 0; pass < 3; ++pass) {
    const int shift = shifts[pass], width = widths[pass];
    const unsigned mask = (1u << width) - 1u;
    for (int j = tid; j < 2048; j += 256) hist[j] = 0;
    __syncthreads();
    for (int i = tid; i < PP; i += 256) {
      const float2 c = conf[rowbase + i];
      const int t = conft[rowbase + i];
      const float score = (t > 0) ? 0.0f : ce_of(c.x, c.y, t);
      const unsigned u = __float_as_uint(score);
      const bool match = (pass == 0) || ((u >> (shift + width)) == prefix);
      if (match) atomicAdd(&hist[(u >> shift) & mask], 1u);
    }
    __syncthreads();
    if (tid == 0) {
      long long c = 0;
      int d = (int)mask;
      for (; d >= 0; --d) {
        c += hist[d];
        if (c >= kk) break;
      }
      if (d < 0) d = 0;  // safety; invariant guarantees break
      sh_prefix = (prefix << width) | (unsigned)d;
      sh_kk = kk - (c - (long long)hist[d]);
    }
    __syncthreads();
    prefix = sh_prefix;
    kk = sh_kk;
    __syncthreads();
  }

  // prefix == T bits (k-th largest score). kk = #ties to include, ascending
  // index order (stable argsort semantics).
  const unsigned Tbits = prefix;
  double local_ce = 0.0;
  __shared__ unsigned wavecnt[4];
  __shared__ long long s_rt;
  if (tid == 0) s_rt = 0;
  __syncthreads();
  const int lane = tid & 63, wave = tid >> 6;

  for (int basei = 0; basei < PP; basei += 256) {
    const int i = basei + tid;
    const float2 c = conf[rowbase + i];
    const int t = conft[rowbase + i];
    const float ce = ce_of(c.x, c.y, t);
    const float score = (t > 0) ? 0.0f : ce;
    const unsigned u = __float_as_uint(score);
    const bool gt = u > Tbits;
    const bool eq = (u == Tbits);
    const unsigned long long bal = __ballot(eq ? 1 : 0);
    if (lane == 0) wavecnt[wave] = (unsigned)__popcll(bal);
    __syncthreads();
    long long cross = s_rt;
    for (int w = 0; w < wave; ++w) cross += wavecnt[w];
    const long long myord = cross + __popcll(bal & ((1ULL << lane) - 1ULL));
    if (gt || (eq && myord < kk)) local_ce += (double)ce;
    __syncthreads();
    if (tid == 0) s_rt += (long long)wavecnt[0] + wavecnt[1] + wavecnt[2] + wavecnt[3];
    __syncthreads();
  }

#pragma unroll
  for (int off = 32; off; off >>= 1) local_ce += __shfl_down(local_ce, off);
  __shared__ double s_ce[4];
  if (lane == 0) s_ce[wave] = local_ce;
  __syncthreads();
  if (tid == 0) ws->ce_neg[b] = (float)(s_ce[0] + s_ce[1] + s_ce[2] + s_ce[3]);
}

// ---------------- K3: finalize ----------------
__global__ __launch_bounds__(64) void k_final(const Ws* __restrict__ ws,
                                              float* __restrict__ out) {
  const int tid = threadIdx.x;
  double np_d = 0.0, ce_sel = 0.0, cnt = 0.0, sl1 = 0.0;
  if (tid < BB) {
    const int npos = ws->num_pos[tid];
    const long long M = (long long)PP - npos;
    long long k = (long long)NEG_RATIO * npos;
    if (k > PP - 1) k = PP - 1;
    np_d = (double)npos;
    sl1 = (double)ws->sum_sl1[tid];
    if (k >= M) {  // case 1: sel covers every prior
      ce_sel = (double)ws->sum_ce_all[tid];
      cnt = (double)PP;
    } else {
      const long long kc = k > 0 ? k : 0;
      ce_sel = (double)ws->sum_ce_pos[tid] + (double)ws->ce_neg[tid];
      cnt = (double)(npos + kc);
    }
  }
#pragma unroll
  for (int off = 32; off; off >>= 1) {
    np_d   += __shfl_down(np_d, off);
    ce_sel += __shfl_down(ce_sel, off);
    cnt    += __shfl_down(cnt, off);
    sl1    += __shfl_down(sl1, off);
  }
  if (tid == 0) {
    const double N = np_d;
    out[0] = (float)(sl1 / (4.0 * N * N));
    out[1] = (float)(ce_sel / cnt / N);
  }
}

extern "C" void kernel_launch(void* const* d_in, const int* in_sizes, int n_in,
                              void* d_out, int out_size, void* d_ws, size_t ws_size,
                              hipStream_t stream) {
  const v4f*    loc   = (const v4f*)d_in[0];
  const v2f*    cf2   = (const v2f*)d_in[1];
  const float2* conf  = (const float2*)d_in[1];
  const v4f*    loct  = (const v4f*)d_in[2];
  const int*    cnft  = (const int*)d_in[3];
  Ws* ws = (Ws*)d_ws;

  hipMemsetAsync(d_ws, 0, sizeof(Ws), stream);
  k_main<<<dim3(NBLK), dim3(256), 0, stream>>>(loc, cf2, loct, cnft, ws->part);
  k_reduce<<<dim3(BB), dim3(64), 0, stream>>>(ws->part, ws);
  k_select<<<dim3(BB), dim3(256), 0, stream>>>(conf, cnft, ws);
  k_final<<<dim3(1), dim3(64), 0, stream>>>(ws, (float*)d_out);
}

// Round 9
// 173.790 us; speedup vs baseline: 3.1712x; 1.0284x over previous
//
#include <hip/hip_runtime.h>
#include <cstdint>

#define BB 32
#define PP 131072
#define NEG_RATIO 3
#define NBLK 2048            // k_main blocks; 64 per batch

typedef float v4f __attribute__((ext_vector_type(4)));
typedef float v2f __attribute__((ext_vector_type(2)));

// One 16-byte partial per k_main block — plain stores, zero contention.
// (R6 lesson: same-line global atomicAdds serialize ~25 ns/op.)
struct Partial {
  float ce_all, ce_pos, sl1;
  int np;
};

struct Ws {
  float sum_sl1[BB];
  float sum_ce_all[BB];
  float sum_ce_pos[BB];
  float ce_neg[BB];
  int   num_pos[BB];
  Partial part[NBLK];
};

__device__ __forceinline__ float sl1sum(v4f a, v4f b) {
  float dx = fabsf(a.x - b.x), dy = fabsf(a.y - b.y),
        dz = fabsf(a.z - b.z), dw = fabsf(a.w - b.w);
  float sx = dx < 1.0f ? 0.5f * dx * dx : dx - 0.5f;
  float sy = dy < 1.0f ? 0.5f * dy * dy : dy - 0.5f;
  float sz = dz < 1.0f ? 0.5f * dz * dz : dz - 0.5f;
  float sw = dw < 1.0f ? 0.5f * dw * dw : dw - 0.5f;
  return (sx + sy) + (sz + sw);
}

__device__ __forceinline__ float ce_fast(float c0, float c1, int t) {
  float m = fmaxf(c0, c1);
  float d = fabsf(c0 - c1);
  float lse = m + __logf(1.0f + __expf(-d));
  return lse - (t ? c1 : c0);
}

// exact-ish version for the (never-taken on bench data) select path
__device__ __forceinline__ float ce_of(float c0, float c1, int t) {
  float m = fmaxf(c0, c1), mn = fminf(c0, c1);
  float lse = m + log1pf(expf(mn - m));
  return lse - (t ? c1 : c0);
}

// ---------------- K_main: fused pass, partial stores, MLP via register budget --
// R8 evidence: __launch_bounds__(256,2) -> VGPR 24->40, 68->43 us (4.1 TB/s).
// The scheduler's occupancy-driven register target was the R1-R7 bottleneck
// (live-range shrink => ~1 load in flight => 2.5 TB/s wall). R9: notch the
// budget to 1 wave/EU (512 VGPR) — last step on this axis.
__global__ __launch_bounds__(256, 1) void k_main(
    const v4f* __restrict__ loc, const v2f* __restrict__ cf2,
    const v4f* __restrict__ loct, const int* __restrict__ tt,
    Partial* __restrict__ part) {
  const int tid = threadIdx.x;
  const int base = blockIdx.x * 2048;

  v4f l[8], g[8];
  v2f c[8];
  int t[8];
#pragma unroll
  for (int k = 0; k < 8; ++k) {
    const int i = base + k * 256 + tid;
    l[k] = __builtin_nontemporal_load(loc + i);   // zero-reuse stream
    g[k] = __builtin_nontemporal_load(loct + i);  // zero-reuse stream
    c[k] = __builtin_nontemporal_load(cf2 + i);   // k_select never runs on real data
    t[k] = __builtin_nontemporal_load(tt + i);
  }

  float a_all = 0.f, a_pos = 0.f, a_sl1 = 0.f;
  int np = 0;
#pragma unroll
  for (int k = 0; k < 8; ++k) {
    const float ce = ce_fast(c[k].x, c[k].y, t[k]);
    const float s  = sl1sum(l[k], g[k]);
    const float m  = t[k] > 0 ? 1.0f : 0.0f;
    a_all += ce;
    a_pos += m * ce;
    a_sl1 += m * s;
    np    += (t[k] > 0);
  }

#pragma unroll
  for (int off = 32; off; off >>= 1) {
    a_all += __shfl_down(a_all, off);
    a_pos += __shfl_down(a_pos, off);
    a_sl1 += __shfl_down(a_sl1, off);
    np    += __shfl_down(np, off);
  }

  __shared__ float s1[4], s2[4], s3[4];
  __shared__ int s4[4];
  const int wave = tid >> 6, lane = tid & 63;
  if (lane == 0) { s1[wave] = a_all; s2[wave] = a_pos; s3[wave] = a_sl1; s4[wave] = np; }
  __syncthreads();
  if (tid == 0) {
    Partial p;
    p.ce_all = (s1[0] + s1[1]) + (s1[2] + s1[3]);
    p.ce_pos = (s2[0] + s2[1]) + (s2[2] + s2[3]);
    p.sl1    = (s3[0] + s3[1]) + (s3[2] + s3[3]);
    p.np     = s4[0] + s4[1] + s4[2] + s4[3];
    part[blockIdx.x] = p;  // plain 16B store, disjoint slot
  }
}

// ---------------- K_reduce: fold 64 partials/batch into finals ----------------
__global__ __launch_bounds__(64) void k_reduce(const Partial* __restrict__ part,
                                               Ws* __restrict__ ws) {
  const int b = blockIdx.x;      // batch
  const int lane = threadIdx.x;  // 0..63
  Partial p = part[b * 64 + lane];
  float all = p.ce_all, pos = p.ce_pos, sl1 = p.sl1;
  int np = p.np;
#pragma unroll
  for (int off = 32; off; off >>= 1) {
    all += __shfl_down(all, off);
    pos += __shfl_down(pos, off);
    sl1 += __shfl_down(sl1, off);
    np  += __shfl_down(np, off);
  }
  if (lane == 0) {
    ws->sum_ce_all[b] = all;
    ws->sum_ce_pos[b] = pos;
    ws->sum_sl1[b]    = sl1;
    ws->num_pos[b]    = np;
  }
}

// ---------------- K2: general top-k negative selection (case 2) ----------------
// Only runs for batches where num_neg < (P - num_pos). For the bench data this
// never triggers (num_neg = P-1 >= M), so the block exits immediately.
__global__ __launch_bounds__(256) void k_select(
    const float2* __restrict__ conf, const int* __restrict__ conft,
    Ws* __restrict__ ws) {
  const int b = blockIdx.x;
  const int npos = ws->num_pos[b];
  const long long M = (long long)PP - npos;
  long long k = (long long)NEG_RATIO * npos;
  if (k > PP - 1) k = PP - 1;
  if (k >= M) return;   // case 1: sel == everything, finalize handles it
  if (k <= 0) return;   // no negatives selected

  const int tid = threadIdx.x;
  const int rowbase = b * PP;

  __shared__ unsigned hist[2048];
  __shared__ unsigned sh_prefix;
  __shared__ long long sh_kk;

  unsigned prefix = 0;
  long long kk = k;
  const int shifts[3] = {21, 10, 0};
  const int widths[3] = {11, 11, 10};

  for (int pass = 0; pass < 3; ++pass) {
    const int shift = shifts[pass], width = widths[pass];
    const unsigned mask = (1u << width) - 1u;
    for (int j = tid; j < 2048; j += 256) hist[j] = 0;
    __syncthreads();
    for (int i = tid; i < PP; i += 256) {
      const float2 c = conf[rowbase + i];
      const int t = conft[rowbase + i];
      const float score = (t > 0) ? 0.0f : ce_of(c.x, c.y, t);
      const unsigned u = __float_as_uint(score);
      const bool match = (pass == 0) || ((u >> (shift + width)) == prefix);
      if (match) atomicAdd(&hist[(u >> shift) & mask], 1u);
    }
    __syncthreads();
    if (tid == 0) {
      long long c = 0;
      int d = (int)mask;
      for (; d >= 0; --d) {
        c += hist[d];
        if (c >= kk) break;
      }
      if (d < 0) d = 0;  // safety; invariant guarantees break
      sh_prefix = (prefix << width) | (unsigned)d;
      sh_kk = kk - (c - (long long)hist[d]);
    }
    __syncthreads();
    prefix = sh_prefix;
    kk = sh_kk;
    __syncthreads();
  }

  // prefix == T bits (k-th largest score). kk = #ties to include, ascending
  // index order (stable argsort semantics).
  const unsigned Tbits = prefix;
  double local_ce = 0.0;
  __shared__ unsigned wavecnt[4];
  __shared__ long long s_rt;
  if (tid == 0) s_rt = 0;
  __syncthreads();
  const int lane = tid & 63, wave = tid >> 6;

  for (int basei = 0; basei < PP; basei += 256) {
    const int i = basei + tid;
    const float2 c = conf[rowbase + i];
    const int t = conft[rowbase + i];
    const float ce = ce_of(c.x, c.y, t);
    const float score = (t > 0) ? 0.0f : ce;
    const unsigned u = __float_as_uint(score);
    const bool gt = u > Tbits;
    const bool eq = (u == Tbits);
    const unsigned long long bal = __ballot(eq ? 1 : 0);
    if (lane == 0) wavecnt[wave] = (unsigned)__popcll(bal);
    __syncthreads();
    long long cross = s_rt;
    for (int w = 0; w < wave; ++w) cross += wavecnt[w];
    const long long myord = cross + __popcll(bal & ((1ULL << lane) - 1ULL));
    if (gt || (eq && myord < kk)) local_ce += (double)ce;
    __syncthreads();
    if (tid == 0) s_rt += (long long)wavecnt[0] + wavecnt[1] + wavecnt[2] + wavecnt[3];
    __syncthreads();
  }

#pragma unroll
  for (int off = 32; off; off >>= 1) local_ce += __shfl_down(local_ce, off);
  __shared__ double s_ce[4];
  if (lane == 0) s_ce[wave] = local_ce;
  __syncthreads();
  if (tid == 0) ws->ce_neg[b] = (float)(s_ce[0] + s_ce[1] + s_ce[2] + s_ce[3]);
}

// ---------------- K3: finalize ----------------
__global__ __launch_bounds__(64) void k_final(const Ws* __restrict__ ws,
                                              float* __restrict__ out) {
  const int tid = threadIdx.x;
  double np_d = 0.0, ce_sel = 0.0, cnt = 0.0, sl1 = 0.0;
  if (tid < BB) {
    const int npos = ws->num_pos[tid];
    const long long M = (long long)PP - npos;
    long long k = (long long)NEG_RATIO * npos;
    if (k > PP - 1) k = PP - 1;
    np_d = (double)npos;
    sl1 = (double)ws->sum_sl1[tid];
    if (k >= M) {  // case 1: sel covers every prior
      ce_sel = (double)ws->sum_ce_all[tid];
      cnt = (double)PP;
    } else {
      const long long kc = k > 0 ? k : 0;
      ce_sel = (double)ws->sum_ce_pos[tid] + (double)ws->ce_neg[tid];
      cnt = (double)(npos + kc);
    }
  }
#pragma unroll
  for (int off = 32; off; off >>= 1) {
    np_d   += __shfl_down(np_d, off);
    ce_sel += __shfl_down(ce_sel, off);
    cnt    += __shfl_down(cnt, off);
    sl1    += __shfl_down(sl1, off);
  }
  if (tid == 0) {
    const double N = np_d;
    out[0] = (float)(sl1 / (4.0 * N * N));
    out[1] = (float)(ce_sel / cnt / N);
  }
}

extern "C" void kernel_launch(void* const* d_in, const int* in_sizes, int n_in,
                              void* d_out, int out_size, void* d_ws, size_t ws_size,
                              hipStream_t stream) {
  const v4f*    loc   = (const v4f*)d_in[0];
  const v2f*    cf2   = (const v2f*)d_in[1];
  const float2* conf  = (const float2*)d_in[1];
  const v4f*    loct  = (const v4f*)d_in[2];
  const int*    cnft  = (const int*)d_in[3];
  Ws* ws = (Ws*)d_ws;

  hipMemsetAsync(d_ws, 0, sizeof(Ws), stream);
  k_main<<<dim3(NBLK), dim3(256), 0, stream>>>(loc, cf2, loct, cnft, ws->part);
  k_reduce<<<dim3(BB), dim3(64), 0, stream>>>(ws->part, ws);
  k_select<<<dim3(BB), dim3(256), 0, stream>>>(conf, cnft, ws);
  k_final<<<dim3(1), dim3(64), 0, stream>>>(ws, (float*)d_out);
}